// Round 2
// baseline (374.545 us; speedup 1.0000x reference)
//
#include <hip/hip_runtime.h>
#include <hip/hip_bf16.h>
#include <stdint.h>

// ---------------------------------------------------------------------------
// OutputLayerReverseSegments: out[b,f,c] = sum_i x[b,c,t_i(f),:] . W_i[p_i(f),:]
//                                        + sum_i b_i[p_i(f)]
// B=64, C=64, T=63, D=256, F=720, partitions k = {1,2,4,8,16,32}
// Strategy: per block = (b, 16-c tile). Sweep f in 16-wide tiles.
//   - x tokens staged fp32->bf16 into a 12-slot LDS sliding window
//     (2 slots per partition, parity of part index) -> x read from HBM once.
//   - W rows for the tile staged fp32->bf16 into LDS (L2-resident source).
//   - One 16x16 MFMA output tile per f-tile; K=1536 split across 4 waves,
//     partial sums reduced through LDS. Partition boundaries inside a tile
//     handled by row-masked double-MFMA.
// ---------------------------------------------------------------------------

#define FDIM 720
#define DDIM 256
#define TDIM 63
#define TC   16

typedef __attribute__((ext_vector_type(8))) short short8;
typedef __attribute__((ext_vector_type(4))) float f32x4;

// LDS layout (bytes)
#define XWIN_OFF 0                       // 12 slots * 16 c * 256 d * 2B = 98304
#define WBUF_OFF 98304                   // 6 i * 16 f * 256 d * 2B    = 49152
#define RED_OFF  (98304 + 49152)         // 4 waves * 256 f32          = 4096
#define LDS_BYTES (98304 + 49152 + 4096) // 151552

__device__ __forceinline__ unsigned short f2bf(float f) {
    uint32_t u = __builtin_bit_cast(uint32_t, f);
    u += 0x7fffu + ((u >> 16) & 1u);   // round-to-nearest-even
    return (unsigned short)(u >> 16);
}
__device__ __forceinline__ uint32_t pk2(float a, float b) {
    return (uint32_t)f2bf(a) | ((uint32_t)f2bf(b) << 16);
}

// partition index / position within part, for partition i at forecast f
__device__ __forceinline__ void jpos(int i, int f, int& j, int& pos) {
    switch (i) {
        case 0: j = 0;       pos = f;            break;
        case 1: j = f / 360; pos = f - 360 * j;  break;
        case 2: j = f / 180; pos = f - 180 * j;  break;
        case 3: j = f / 90;  pos = f - 90 * j;   break;
        case 4: j = f / 45;  pos = f - 45 * j;   break;
        default:
            if (f < 368) { j = f / 23;  pos = f - 23 * j; }
            else { int g = f - 368; int q = g / 22; j = 16 + q; pos = g - 22 * q; }
            break;
    }
}
__device__ __forceinline__ int startf(int i, int j) {
    switch (i) {
        case 0: return 0;
        case 1: return 360 * j;
        case 2: return 180 * j;
        case 3: return 90 * j;
        case 4: return 45 * j;
        default: return (j < 16) ? 23 * j : 368 + 22 * (j - 16);
    }
}

__global__ __launch_bounds__(256, 1) void olrs_main(
    const float* __restrict__ x,
    const float* __restrict__ W0, const float* __restrict__ b0,
    const float* __restrict__ W1, const float* __restrict__ b1,
    const float* __restrict__ W2, const float* __restrict__ b2,
    const float* __restrict__ W3, const float* __restrict__ b3,
    const float* __restrict__ W4, const float* __restrict__ b4,
    const float* __restrict__ W5, const float* __restrict__ b5,
    float* __restrict__ out)
{
    extern __shared__ char lds[];
    const int tid  = threadIdx.x;
    const int wave = tid >> 6;
    const int lane = tid & 63;
    const int blk  = blockIdx.x;
    const int b    = blk >> 2;
    const int c0   = (blk & 3) * TC;

    const float* Wp[6] = {W0, W1, W2, W3, W4, W5};
    const float* bp[6] = {b0, b1, b2, b3, b4, b5};
    const int TBASE[6] = {0, 1, 3, 7, 15, 31};

    int prev_jhi[6] = {-1, -1, -1, -1, -1, -1};

    const int m15  = lane & 15;   // A row (f) / B col (c) within fragment
    const int koct = lane >> 4;   // k-octet selector

    for (int f0 = 0; f0 < FDIM; f0 += 16) {
        // ---- per-tile, per-partition uniform parameters
        int jlo[6], jhi[6], fb[6];
        #pragma unroll
        for (int i = 0; i < 6; i++) {
            int j0, p0, j1, p1;
            jpos(i, f0, j0, p0);
            jpos(i, f0 + 15, j1, p1);
            jlo[i] = j0; jhi[i] = j1;
            fb[i] = (j1 > j0) ? (startf(i, j1) - f0) : 16;
        }

        // ---- stage new x token slots (fp32 global -> bf16 LDS, swizzled)
        #pragma unroll
        for (int i = 0; i < 6; i++) {
            if (jhi[i] > prev_jhi[i]) {
                prev_jhi[i] = jhi[i];
                const int t    = TBASE[i] + jhi[i];
                const int slot = i * 2 + (jhi[i] & 1);
                const int c    = tid >> 4;
                const int t15  = tid & 15;
                const float* src = x + (((size_t)(b * 64 + c0 + c)) * TDIM + t) * DDIM;
                char* dst = lds + XWIN_OFF + slot * 8192 + c * 512;
                #pragma unroll
                for (int rep = 0; rep < 4; rep++) {
                    const int d0 = (t15 + rep * 16) * 4;   // float index
                    float4 v = *(const float4*)(src + d0);
                    uint2 pk;
                    pk.x = pk2(v.x, v.y);
                    pk.y = pk2(v.z, v.w);
                    *(uint2*)(dst + ((d0 * 2) ^ ((c & 7) << 4))) = pk;
                }
            }
        }

        // ---- stage W rows for this tile (fp32 L2 -> bf16 LDS, swizzled)
        #pragma unroll
        for (int rep = 0; rep < 24; rep++) {
            const int id  = tid + rep * 256;  // 0..6143 float4-chunks
            const int row = id >> 6;          // 0..95 = i*16 + fs
            const int g4  = id & 63;          // float4 within the 256-d row
            const int i   = row >> 4;
            const int fs  = row & 15;
            int j, pos;
            jpos(i, f0 + fs, j, pos);
            const float* src = Wp[i] + (size_t)pos * DDIM + g4 * 4;
            float4 v = *(const float4*)src;
            uint2 pk;
            pk.x = pk2(v.x, v.y);
            pk.y = pk2(v.z, v.w);
            *(uint2*)(lds + WBUF_OFF + row * 512 + ((g4 * 8) ^ ((fs & 7) << 4))) = pk;
        }

        __syncthreads();

        // ---- MFMA: K split across 4 waves (each: 12 k-steps of 32)
        f32x4 acc = {0.f, 0.f, 0.f, 0.f};
        #pragma unroll
        for (int i = 0; i < 6; i++) {
            const int slo = i * 2 + (jlo[i] & 1);
            const int shi = i * 2 + (jhi[i] & 1);
            #pragma unroll
            for (int r = 0; r < 2; r++) {
                const int ks = wave + r * 4;         // 0..7
                const int kd = ks * 32 + koct * 8;   // element-k of this frag
                const int swz = ((m15 & 7) << 4);
                short8 a = *(const short8*)(lds + WBUF_OFF + (i * 16 + m15) * 512
                                            + ((kd * 2) ^ swz));
                short8 blo = *(const short8*)(lds + XWIN_OFF + slo * 8192 + m15 * 512
                                              + ((kd * 2) ^ swz));
                if (fb[i] == 16) {
                    acc = __builtin_amdgcn_mfma_f32_16x16x32_bf16(a, blo, acc, 0, 0, 0);
                } else {
                    short8 bhi = *(const short8*)(lds + XWIN_OFF + shi * 8192 + m15 * 512
                                                  + ((kd * 2) ^ swz));
                    short8 z;
                    #pragma unroll
                    for (int q = 0; q < 8; q++) z[q] = 0;
                    short8 alo = (m15 < fb[i]) ? a : z;
                    short8 ahi = (m15 < fb[i]) ? z : a;
                    acc = __builtin_amdgcn_mfma_f32_16x16x32_bf16(alo, blo, acc, 0, 0, 0);
                    acc = __builtin_amdgcn_mfma_f32_16x16x32_bf16(ahi, bhi, acc, 0, 0, 0);
                }
            }
        }

        // ---- cross-wave reduce via LDS
        float* red = (float*)(lds + RED_OFF);
        {
            const int col = lane & 15;
            #pragma unroll
            for (int rg = 0; rg < 4; rg++) {
                const int row = (lane >> 4) * 4 + rg;
                red[wave * 256 + row * 16 + col] = acc[rg];
            }
        }
        __syncthreads();

        // ---- epilogue: sum partials + bias, coalesced store
        {
            const int row = tid >> 4;
            const int col = tid & 15;
            float s = red[0 * 256 + tid] + red[1 * 256 + tid]
                    + red[2 * 256 + tid] + red[3 * 256 + tid];
            const int f = f0 + row;
            float bias = 0.f;
            #pragma unroll
            for (int i = 0; i < 6; i++) {
                int j, pos;
                jpos(i, f, j, pos);
                bias += bp[i][pos];
            }
            out[((size_t)b * FDIM + f) * 64 + c0 + col] = s + bias;
        }
        __syncthreads();   // protect red/xwin/Wbuf before next tile's staging
    }
}

extern "C" void kernel_launch(void* const* d_in, const int* in_sizes, int n_in,
                              void* d_out, int out_size, void* d_ws, size_t ws_size,
                              hipStream_t stream) {
    (void)in_sizes; (void)n_in; (void)d_ws; (void)ws_size; (void)out_size;

    const float* x  = (const float*)d_in[0];
    const float* W0 = (const float*)d_in[1];
    const float* b0 = (const float*)d_in[2];
    const float* W1 = (const float*)d_in[3];
    const float* b1 = (const float*)d_in[4];
    const float* W2 = (const float*)d_in[5];
    const float* b2 = (const float*)d_in[6];
    const float* W3 = (const float*)d_in[7];
    const float* b3 = (const float*)d_in[8];
    const float* W4 = (const float*)d_in[9];
    const float* b4 = (const float*)d_in[10];
    const float* W5 = (const float*)d_in[11];
    const float* b5 = (const float*)d_in[12];
    float* out = (float*)d_out;

    hipFuncSetAttribute((const void*)olrs_main,
                        hipFuncAttributeMaxDynamicSharedMemorySize, LDS_BYTES);

    olrs_main<<<dim3(256), dim3(256), LDS_BYTES, stream>>>(
        x, W0, b0, W1, b1, W2, b2, W3, b3, W4, b4, W5, b5, out);
}

// Round 3
// 189.184 us; speedup vs baseline: 1.9798x; 1.9798x over previous
//
#include <hip/hip_runtime.h>
#include <stdint.h>

// ---------------------------------------------------------------------------
// OutputLayerReverseSegments, round 3: wave-independent max-TLP design.
// out[b,f,c] = sum_i x[b,c,t_i(f),:] . W_i[p_i(f),:] + sum_i b_i[p_i(f)]
// B=64, C=64, T=63, D=256, F=720, partitions k = {1,2,4,8,16,32}
//
// One wave owns one 16f x 16c output tile, full K=1536 (6 partitions x 8
// k-steps of 32). No LDS, no barriers -> occupancy limited only by VGPRs.
// 11520 waves = 2880 blocks x 256 thr.
// W is pre-packed to bf16 in exact MFMA fragment order in d_ws by a prep
// kernel (1 coalesced 16B/lane load per fragment, no convert VALU); bias
// pre-summed into a 720-entry table. Fallback path loads W fp32 directly
// if ws_size is too small.
// ---------------------------------------------------------------------------

#define FDIM 720
#define DDIM 256
#define TDIM 63
#define NTILE 45                       // 720/16 f-tiles
#define NWAVE (NTILE * 256)            // 11520 waves
#define WTAB_BYTES (NTILE * 6 * 8 * 1024)   // 2,211,840: frag table
#define BIAS_OFF   WTAB_BYTES
#define WS_NEED    (WTAB_BYTES + FDIM * 4)

typedef __attribute__((ext_vector_type(8))) short short8;
typedef __attribute__((ext_vector_type(4))) float f32x4;

__constant__ const int TBASE[6] = {0, 1, 3, 7, 15, 31};

// partition index / position within part, for partition i at forecast f
__device__ __forceinline__ void jpos(int i, int f, int& j, int& pos) {
    switch (i) {
        case 0: j = 0;       pos = f;            break;
        case 1: j = f / 360; pos = f - 360 * j;  break;
        case 2: j = f / 180; pos = f - 180 * j;  break;
        case 3: j = f / 90;  pos = f - 90 * j;   break;
        case 4: j = f / 45;  pos = f - 45 * j;   break;
        default:
            if (f < 368) { j = f / 23;  pos = f - 23 * j; }
            else { int g = f - 368; int q = g / 22; j = 16 + q; pos = g - 22 * q; }
            break;
    }
}
__device__ __forceinline__ int startf(int i, int j) {
    switch (i) {
        case 0: return 0;
        case 1: return 360 * j;
        case 2: return 180 * j;
        case 3: return 90 * j;
        case 4: return 45 * j;
        default: return (j < 16) ? 23 * j : 368 + 22 * (j - 16);
    }
}

// pack 2 f32 -> 2 bf16 (round-half-up) in one u32: 2 adds + 1 v_perm
__device__ __forceinline__ uint32_t pkru(float a, float b) {
    uint32_t ua = __builtin_bit_cast(uint32_t, a) + 0x8000u;
    uint32_t ub = __builtin_bit_cast(uint32_t, b) + 0x8000u;
    return __builtin_amdgcn_perm(ub, ua, 0x07060302u);
}

// load 8 consecutive fp32 and pack to a bf16 short8 fragment
__device__ __forceinline__ short8 loadpack(const float* p) {
    float4 v0 = *(const float4*)p;
    float4 v1 = *(const float4*)(p + 4);
    uint4 u;
    u.x = pkru(v0.x, v0.y);
    u.y = pkru(v0.z, v0.w);
    u.z = pkru(v1.x, v1.y);
    u.w = pkru(v1.z, v1.w);
    return __builtin_bit_cast(short8, u);
}

// ---------------------------------------------------------------------------
// Prep: pack W into bf16 fragment table + bias-sum table, both in d_ws.
// Table layout: chunk = (ft*6 + i)*8 + ks; within chunk, lane*16 bytes holds
// W_i[pos(i, ft*16 + (lane&15)), ks*32 + (lane>>4)*8 .. +8) as bf16.
// ---------------------------------------------------------------------------
__global__ void olrs_prep(
    const float* __restrict__ W0, const float* __restrict__ b0,
    const float* __restrict__ W1, const float* __restrict__ b1,
    const float* __restrict__ W2, const float* __restrict__ b2,
    const float* __restrict__ W3, const float* __restrict__ b3,
    const float* __restrict__ W4, const float* __restrict__ b4,
    const float* __restrict__ W5, const float* __restrict__ b5,
    char* __restrict__ ws)
{
    const float* Wp[6] = {W0, W1, W2, W3, W4, W5};
    const float* bp[6] = {b0, b1, b2, b3, b4, b5};
    const int gid   = blockIdx.x * 256 + threadIdx.x;
    const int lane  = gid & 63;
    const int chunk = gid >> 6;
    if (chunk < NTILE * 6 * 8) {
        const int ks = chunk & 7;
        const int fi = chunk >> 3;         // ft*6 + i
        const int i  = fi % 6;
        const int ft = fi / 6;
        const int m15  = lane & 15;
        const int koct = lane >> 4;
        int j, pos;
        jpos(i, ft * 16 + m15, j, pos);
        const float* src = Wp[i] + (size_t)pos * DDIM + ks * 32 + koct * 8;
        float4 v0 = *(const float4*)src;
        float4 v1 = *(const float4*)(src + 4);
        uint4 u;
        u.x = pkru(v0.x, v0.y);
        u.y = pkru(v0.z, v0.w);
        u.z = pkru(v1.x, v1.y);
        u.w = pkru(v1.z, v1.w);
        *(uint4*)(ws + (size_t)chunk * 1024 + lane * 16) = u;
    }
    if (gid < FDIM) {
        float s = 0.f;
        #pragma unroll
        for (int i = 0; i < 6; i++) {
            int j, pos;
            jpos(i, gid, j, pos);
            s += bp[i][pos];
        }
        *(float*)(ws + BIAS_OFF + gid * 4) = s;
    }
}

// ---------------------------------------------------------------------------
// Main: one wave per (b, c-tile, f-tile).
// ---------------------------------------------------------------------------
template<bool PREW>
__global__ __launch_bounds__(256, 4) void olrs_main(
    const float* __restrict__ x,
    const float* __restrict__ W0, const float* __restrict__ b0,
    const float* __restrict__ W1, const float* __restrict__ b1,
    const float* __restrict__ W2, const float* __restrict__ b2,
    const float* __restrict__ W3, const float* __restrict__ b3,
    const float* __restrict__ W4, const float* __restrict__ b4,
    const float* __restrict__ W5, const float* __restrict__ b5,
    const char* __restrict__ ws,
    float* __restrict__ out)
{
    const float* Wp[6] = {W0, W1, W2, W3, W4, W5};
    const float* bp[6] = {b0, b1, b2, b3, b4, b5};

    const int wid  = blockIdx.x * 4 + (threadIdx.x >> 6);
    const int lane = threadIdx.x & 63;
    const int ft   = wid % NTILE;
    const int bc   = wid / NTILE;
    const int b    = bc >> 2;
    const int c0   = (bc & 3) << 4;
    const int f0   = ft << 4;
    const int m15  = lane & 15;
    const int koct = lane >> 4;

    // x row base for this lane's c (token index added per partition)
    const size_t xrow = (size_t)(b * 64 + c0 + m15) * TDIM;

    f32x4 acc = {0.f, 0.f, 0.f, 0.f};

    #pragma unroll
    for (int i = 0; i < 6; i++) {
        // uniform tile parameters for this partition
        int jlo, plo, jhi, phi;
        jpos(i, f0, jlo, plo);
        jpos(i, f0 + 15, jhi, phi);
        const bool cross = (jhi > jlo);
        const int fb = cross ? (startf(i, jhi) - f0) : 16;

        const float* xlo = x + (xrow + TBASE[i] + jlo) * DDIM;
        const float* xhi = x + (xrow + TBASE[i] + jhi) * DDIM;

        // W fragment source
        const char* wtab = nullptr;
        const float* wsrc = nullptr;
        if (PREW) {
            wtab = ws + ((size_t)(ft * 6 + i) * 8) * 1024 + lane * 16;
        } else {
            int jw, pw;
            jpos(i, f0 + m15, jw, pw);
            wsrc = Wp[i] + (size_t)pw * DDIM;
        }

        #pragma unroll
        for (int ks = 0; ks < 8; ks++) {
            const int d0 = ks * 32 + koct * 8;
            short8 a;
            if (PREW) a = *(const short8*)(wtab + ks * 1024);
            else      a = loadpack(wsrc + d0);

            short8 blo = loadpack(xlo + d0);
            if (!cross) {
                acc = __builtin_amdgcn_mfma_f32_16x16x32_bf16(a, blo, acc, 0, 0, 0);
            } else {
                short8 bhi = loadpack(xhi + d0);
                short8 z;
                #pragma unroll
                for (int q = 0; q < 8; q++) z[q] = 0;
                short8 alo = (m15 < fb) ? a : z;
                short8 ahi = (m15 < fb) ? z : a;
                acc = __builtin_amdgcn_mfma_f32_16x16x32_bf16(alo, blo, acc, 0, 0, 0);
                acc = __builtin_amdgcn_mfma_f32_16x16x32_bf16(ahi, bhi, acc, 0, 0, 0);
            }
        }
    }

    // epilogue: C layout col=lane&15, row=(lane>>4)*4+rg  (verified round 2)
    const float* btab = (const float*)(ws + BIAS_OFF);
    #pragma unroll
    for (int rg = 0; rg < 4; rg++) {
        const int f = f0 + koct * 4 + rg;
        float bias;
        if (PREW) {
            bias = btab[f];
        } else {
            bias = 0.f;
            #pragma unroll
            for (int i = 0; i < 6; i++) {
                int j, pos;
                jpos(i, f, j, pos);
                bias += bp[i][pos];
            }
        }
        out[((size_t)b * FDIM + f) * 64 + c0 + m15] = acc[rg] + bias;
    }
}

extern "C" void kernel_launch(void* const* d_in, const int* in_sizes, int n_in,
                              void* d_out, int out_size, void* d_ws, size_t ws_size,
                              hipStream_t stream) {
    (void)in_sizes; (void)n_in; (void)out_size;

    const float* x  = (const float*)d_in[0];
    const float* W0 = (const float*)d_in[1];
    const float* b0 = (const float*)d_in[2];
    const float* W1 = (const float*)d_in[3];
    const float* b1 = (const float*)d_in[4];
    const float* W2 = (const float*)d_in[5];
    const float* b2 = (const float*)d_in[6];
    const float* W3 = (const float*)d_in[7];
    const float* b3 = (const float*)d_in[8];
    const float* W4 = (const float*)d_in[9];
    const float* b4 = (const float*)d_in[10];
    const float* W5 = (const float*)d_in[11];
    const float* b5 = (const float*)d_in[12];
    float* out = (float*)d_out;

    const int nblocks = NWAVE / 4;  // 2880 blocks x 4 waves

    if (ws_size >= (size_t)WS_NEED) {
        char* ws = (char*)d_ws;
        olrs_prep<<<dim3((NTILE * 6 * 8 * 64 + 255) / 256), dim3(256), 0, stream>>>(
            W0, b0, W1, b1, W2, b2, W3, b3, W4, b4, W5, b5, ws);
        olrs_main<true><<<dim3(nblocks), dim3(256), 0, stream>>>(
            x, W0, b0, W1, b1, W2, b2, W3, b3, W4, b4, W5, b5, ws, out);
    } else {
        olrs_main<false><<<dim3(nblocks), dim3(256), 0, stream>>>(
            x, W0, b0, W1, b1, W2, b2, W3, b3, W4, b4, W5, b5,
            (const char*)d_ws, out);
    }
}

// Round 4
// 132.155 us; speedup vs baseline: 2.8341x; 1.4315x over previous
//
#include <hip/hip_runtime.h>
#include <stdint.h>

// ---------------------------------------------------------------------------
// OutputLayerReverseSegments, round 4: token-aligned tiles, x read ONCE.
// out[b,f,c] = sum_i x[b,c,t_i(f),:] . W_i[p_i(f),:] + sum_i b_i[p_i(f)]
// B=64, C=64, T=63, D=256, F=720, partitions k = {1,2,4,8,16,32}
//
// Wave = (token tok=0..62, 16-c tile). The wave loads its single x token
// (16c x 256d) once into registers (bf16 frags), then sweeps the part's
// ceil(len/16) f-subtiles: 8 MFMA vs pre-packed bf16 W fragments (2.4 MB
// table in d_ws, L2-resident), atomicAdd into out. x HBM traffic = 264 MB
// exactly (1.0x). Init kernel writes out = bias(f) first (replay-safe).
// Schedule: wid = tok*256 + ntile -> longest parts dispatched first.
// ---------------------------------------------------------------------------

#define FDIM 720
#define DDIM 256
#define TDIM 63
#define NSUBTOT 299                       // sum over (i,j) of ceil(len/16)
#define TAB_BYTES ((size_t)NSUBTOT * 8 * 1024)   // 2,449,408

typedef __attribute__((ext_vector_type(8))) short short8;
typedef __attribute__((ext_vector_type(4))) float f32x4;

// pack 2 f32 -> 2 bf16 (round-half-up) in one u32: 2 adds + 1 v_perm
__device__ __forceinline__ uint32_t pkru(float a, float b) {
    uint32_t ua = __builtin_bit_cast(uint32_t, a) + 0x8000u;
    uint32_t ub = __builtin_bit_cast(uint32_t, b) + 0x8000u;
    return __builtin_amdgcn_perm(ub, ua, 0x07060302u);
}
__device__ __forceinline__ short8 loadpack(const float* p) {
    float4 v0 = *(const float4*)p;
    float4 v1 = *(const float4*)(p + 4);
    uint4 u;
    u.x = pkru(v0.x, v0.y);
    u.y = pkru(v0.z, v0.w);
    u.z = pkru(v1.x, v1.y);
    u.w = pkru(v1.z, v1.w);
    return __builtin_bit_cast(short8, u);
}

// partition index / position within part, for partition i at forecast f
__device__ __forceinline__ void jpos(int i, int f, int& j, int& pos) {
    switch (i) {
        case 0: j = 0;       pos = f;            break;
        case 1: j = f / 360; pos = f - 360 * j;  break;
        case 2: j = f / 180; pos = f - 180 * j;  break;
        case 3: j = f / 90;  pos = f - 90 * j;   break;
        case 4: j = f / 45;  pos = f - 45 * j;   break;
        default:
            if (f < 368) { j = f / 23;  pos = f - 23 * j; }
            else { int g = f - 368; int q = g / 22; j = 16 + q; pos = g - 22 * q; }
            break;
    }
}

// per-token parameters (branchy: no runtime-indexed arrays -> no scratch)
__device__ __forceinline__ void tok_params(int tok, int& len, int& ns,
                                           int& start, int& tabsub) {
    if (tok < 1)       { len = 720; ns = 45; start = 0;
                         tabsub = 0 + tok * 45; }
    else if (tok < 3)  { int j = tok - 1;  len = 360; ns = 23; start = 360 * j;
                         tabsub = 45 + j * 23; }
    else if (tok < 7)  { int j = tok - 3;  len = 180; ns = 12; start = 180 * j;
                         tabsub = 91 + j * 12; }
    else if (tok < 15) { int j = tok - 7;  len = 90;  ns = 6;  start = 90 * j;
                         tabsub = 139 + j * 6; }
    else if (tok < 31) { int j = tok - 15; len = 45;  ns = 3;  start = 45 * j;
                         tabsub = 187 + j * 3; }
    else               { int j = tok - 31;
                         len = (j < 16) ? 23 : 22;
                         start = (j < 16) ? 23 * j : 368 + 22 * (j - 16);
                         ns = 2; tabsub = 235 + j * 2; }
}

// ---------------------------------------------------------------------------
// Prep: build bf16 W fragment table in d_ws.
// frag fid = (tabsub(i,j) + s)*8 + ks; lane*16B holds
// W_i[s*16+(lane&15)][ks*32+(lane>>4)*8 ..+8) as bf16 (zeros if row >= len).
// ---------------------------------------------------------------------------
__global__ __launch_bounds__(256) void olrs_prep(
    const float* __restrict__ W0, const float* __restrict__ W1,
    const float* __restrict__ W2, const float* __restrict__ W3,
    const float* __restrict__ W4, const float* __restrict__ W5,
    char* __restrict__ ws)
{
    const int gid  = blockIdx.x * 256 + threadIdx.x;
    const int lane = gid & 63;
    const int fid  = gid >> 6;
    if (fid >= NSUBTOT * 8) return;
    const int ks = fid & 7;
    const int g  = fid >> 3;      // global subtile 0..298

    int len; const float* W;
    int s;
    if (g < 45)       { W = W0; len = 720; s = g; }
    else if (g < 91)  { int g2 = g - 45;  W = W1; len = 360; s = g2 % 23; }
    else if (g < 139) { int g2 = g - 91;  W = W2; len = 180; s = g2 % 12; }
    else if (g < 187) { int g2 = g - 139; W = W3; len = 90;  s = g2 % 6; }
    else if (g < 235) { int g2 = g - 187; W = W4; len = 45;  s = g2 % 3; }
    else              { int g2 = g - 235; W = W5; int j = g2 >> 1;
                        len = (j < 16) ? 23 : 22; s = g2 & 1; }

    const int m15  = lane & 15;
    const int koct = lane >> 4;
    const int pos  = s * 16 + m15;
    uint4 u = {0u, 0u, 0u, 0u};
    if (pos < len) {
        const float* src = W + (size_t)pos * DDIM + ks * 32 + koct * 8;
        float4 v0 = *(const float4*)src;
        float4 v1 = *(const float4*)(src + 4);
        u.x = pkru(v0.x, v0.y);
        u.y = pkru(v0.z, v0.w);
        u.z = pkru(v1.x, v1.y);
        u.w = pkru(v1.z, v1.w);
    }
    *(uint4*)(ws + (size_t)fid * 1024 + lane * 16) = u;
}

// ---------------------------------------------------------------------------
// Init: out[b,f,c] = sum_i b_i[pos(i,f)]  (full overwrite -> replay-safe)
// ---------------------------------------------------------------------------
__global__ __launch_bounds__(256) void olrs_init(
    const float* __restrict__ b0, const float* __restrict__ b1,
    const float* __restrict__ b2, const float* __restrict__ b3,
    const float* __restrict__ b4, const float* __restrict__ b5,
    float* __restrict__ out)
{
    const int gid = blockIdx.x * 256 + threadIdx.x;
    if (gid >= 64 * FDIM * 64) return;
    const int f = (gid >> 6) % FDIM;
    int j, p;
    float s = 0.f;
    jpos(0, f, j, p); s += b0[p];
    jpos(1, f, j, p); s += b1[p];
    jpos(2, f, j, p); s += b2[p];
    jpos(3, f, j, p); s += b3[p];
    jpos(4, f, j, p); s += b4[p];
    jpos(5, f, j, p); s += b5[p];
    out[gid] = s;
}

// ---------------------------------------------------------------------------
// Main: wave = (tok, ntile). x token in registers, sweep f-subtiles,
// atomicAdd contributions into out.
// ---------------------------------------------------------------------------
__global__ __launch_bounds__(256) void olrs_main(
    const float* __restrict__ x,
    const char* __restrict__ ws,
    float* __restrict__ out)
{
    const int wid   = blockIdx.x * 4 + (threadIdx.x >> 6);
    const int lane  = threadIdx.x & 63;
    const int tok   = wid >> 8;      // 0..62  (long parts first)
    const int ntile = wid & 255;
    const int b     = ntile >> 2;
    const int c0    = (ntile & 3) << 4;
    const int m15   = lane & 15;
    const int koct  = lane >> 4;

    int len, ns, start, tabsub;
    tok_params(tok, len, ns, start, tabsub);

    // ---- load this wave's x token once: 16c x 256d fp32 -> bf16 frags
    const float* xp = x + (((size_t)(b * 64 + c0 + m15)) * TDIM + tok) * DDIM;
    short8 xf[8];
    #pragma unroll
    for (int ks = 0; ks < 8; ks++)
        xf[ks] = loadpack(xp + ks * 32 + koct * 8);

    const char* tab = ws + (size_t)tabsub * 8192 + lane * 16;
    float* obase = out + ((size_t)b * FDIM + start) * 64 + c0 + m15;

    for (int s = 0; s < ns; s++) {
        f32x4 a0 = {0.f, 0.f, 0.f, 0.f};
        f32x4 a1 = {0.f, 0.f, 0.f, 0.f};
        const char* tsub = tab + (size_t)s * 8192;
        #pragma unroll
        for (int ks = 0; ks < 8; ks += 2) {
            short8 w0 = *(const short8*)(tsub + ks * 1024);
            short8 w1 = *(const short8*)(tsub + (ks + 1) * 1024);
            a0 = __builtin_amdgcn_mfma_f32_16x16x32_bf16(w0, xf[ks],     a0, 0, 0, 0);
            a1 = __builtin_amdgcn_mfma_f32_16x16x32_bf16(w1, xf[ks + 1], a1, 0, 0, 0);
        }
        const int fl0 = s * 16 + koct * 4;
        #pragma unroll
        for (int rg = 0; rg < 4; rg++) {
            const int fl = fl0 + rg;
            if (fl < len) atomicAdd(obase + (size_t)fl * 64, a0[rg] + a1[rg]);
        }
    }
}

// ---------------------------------------------------------------------------
// Fallback (ws too small): round-3 wave-independent kernel, direct W loads.
// ---------------------------------------------------------------------------
__device__ __forceinline__ int startf(int i, int j) {
    switch (i) {
        case 0: return 0;
        case 1: return 360 * j;
        case 2: return 180 * j;
        case 3: return 90 * j;
        case 4: return 45 * j;
        default: return (j < 16) ? 23 * j : 368 + 22 * (j - 16);
    }
}

__global__ __launch_bounds__(256) void olrs_fb(
    const float* __restrict__ x,
    const float* __restrict__ W0, const float* __restrict__ b0,
    const float* __restrict__ W1, const float* __restrict__ b1,
    const float* __restrict__ W2, const float* __restrict__ b2,
    const float* __restrict__ W3, const float* __restrict__ b3,
    const float* __restrict__ W4, const float* __restrict__ b4,
    const float* __restrict__ W5, const float* __restrict__ b5,
    float* __restrict__ out)
{
    const float* Wp[6] = {W0, W1, W2, W3, W4, W5};
    const float* bp[6] = {b0, b1, b2, b3, b4, b5};
    const int TB[6] = {0, 1, 3, 7, 15, 31};

    const int wid  = blockIdx.x * 4 + (threadIdx.x >> 6);
    const int lane = threadIdx.x & 63;
    const int ft   = wid % 45;
    const int bc   = wid / 45;
    const int b    = bc >> 2;
    const int c0   = (bc & 3) << 4;
    const int f0   = ft << 4;
    const int m15  = lane & 15;
    const int koct = lane >> 4;
    const size_t xrow = (size_t)(b * 64 + c0 + m15) * TDIM;

    f32x4 acc = {0.f, 0.f, 0.f, 0.f};
    #pragma unroll
    for (int i = 0; i < 6; i++) {
        int jlo, plo, jhi, phi;
        jpos(i, f0, jlo, plo);
        jpos(i, f0 + 15, jhi, phi);
        const bool cross = (jhi > jlo);
        const int fb = cross ? (startf(i, jhi) - f0) : 16;
        const float* xlo = x + (xrow + TB[i] + jlo) * DDIM;
        const float* xhi = x + (xrow + TB[i] + jhi) * DDIM;
        int jw, pw;
        jpos(i, f0 + m15, jw, pw);
        const float* wsrc = Wp[i] + (size_t)pw * DDIM;
        #pragma unroll
        for (int ks = 0; ks < 8; ks++) {
            const int d0 = ks * 32 + koct * 8;
            short8 a = loadpack(wsrc + d0);
            short8 blo = loadpack(xlo + d0);
            if (!cross) {
                acc = __builtin_amdgcn_mfma_f32_16x16x32_bf16(a, blo, acc, 0, 0, 0);
            } else {
                short8 bhi = loadpack(xhi + d0);
                short8 z;
                #pragma unroll
                for (int q = 0; q < 8; q++) z[q] = 0;
                short8 alo = (m15 < fb) ? a : z;
                short8 ahi = (m15 < fb) ? z : a;
                acc = __builtin_amdgcn_mfma_f32_16x16x32_bf16(alo, blo, acc, 0, 0, 0);
                acc = __builtin_amdgcn_mfma_f32_16x16x32_bf16(ahi, bhi, acc, 0, 0, 0);
            }
        }
    }
    #pragma unroll
    for (int rg = 0; rg < 4; rg++) {
        const int f = f0 + koct * 4 + rg;
        float bias = 0.f;
        #pragma unroll
        for (int i = 0; i < 6; i++) {
            int j, pos;
            jpos(i, f, j, pos);
            bias += bp[i][pos];
        }
        out[((size_t)b * FDIM + f) * 64 + c0 + m15] = acc[rg] + bias;
    }
}

extern "C" void kernel_launch(void* const* d_in, const int* in_sizes, int n_in,
                              void* d_out, int out_size, void* d_ws, size_t ws_size,
                              hipStream_t stream) {
    (void)in_sizes; (void)n_in; (void)out_size;

    const float* x  = (const float*)d_in[0];
    const float* W0 = (const float*)d_in[1];
    const float* b0 = (const float*)d_in[2];
    const float* W1 = (const float*)d_in[3];
    const float* b1 = (const float*)d_in[4];
    const float* W2 = (const float*)d_in[5];
    const float* b2 = (const float*)d_in[6];
    const float* W3 = (const float*)d_in[7];
    const float* b3 = (const float*)d_in[8];
    const float* W4 = (const float*)d_in[9];
    const float* b4 = (const float*)d_in[10];
    const float* W5 = (const float*)d_in[11];
    const float* b5 = (const float*)d_in[12];
    float* out = (float*)d_out;

    if (ws_size >= TAB_BYTES) {
        char* ws = (char*)d_ws;
        olrs_prep<<<dim3((NSUBTOT * 8 * 64 + 255) / 256), dim3(256), 0, stream>>>(
            W0, W1, W2, W3, W4, W5, ws);
        olrs_init<<<dim3(64 * FDIM * 64 / 256), dim3(256), 0, stream>>>(
            b0, b1, b2, b3, b4, b5, out);
        olrs_main<<<dim3(63 * 256 / 4), dim3(256), 0, stream>>>(x, ws, out);
    } else {
        olrs_fb<<<dim3(45 * 256 * 4 / 4), dim3(256), 0, stream>>>(
            x, W0, b0, W1, b1, W2, b2, W3, b3, W4, b4, W5, b5, out);
    }
}